// Round 1
// baseline (149.569 us; speedup 1.0000x reference)
//
#include <hip/hip_runtime.h>

#define FD     41024   // FEATURES_DIM = 64*(64*10+1)
#define KBASE  641     // 64*10+1
#define SLDS   325     // odd stride: bank = (5r+c) mod 32 -> conflict-free over 32 rows
#define NB_MAX 1024
#define W1S    520     // W1 LDS stride: bank = (8o+l+8j) mod 32 -> worst 2-way (free)

// workspace layout (int32 units)
#define WS_OFF0  0                        // [1024][64] opp-piece offsets (h[0:256] via W_my)
#define WS_OFF1  (NB_MAX*64)              // [1024][64] my-piece offsets  (h[256:512] via W_opp)
#define WS_N0    (2*NB_MAX*64)            // [1024]
#define WS_N1    (WS_N0 + NB_MAX)
#define WS_KMY   (WS_N1 + NB_MAX)         // my king square
#define WS_KOPP  (WS_KMY + NB_MAX)        // opp king square
#define WS_H     (WS_KOPP + NB_MAX)       // float h[1024][512] (post bias+relu)

// ---------------------------------------------------------------------------
// Node 1: classify squares into offset lists + kings. 4 boards per block
// (one wave per board), 256 blocks instead of 1024.
// ---------------------------------------------------------------------------
__global__ __launch_bounds__(256) void classify4(
    const int* __restrict__ boards, int* __restrict__ ws, int nb)
{
    __shared__ int s_off0[4][64], s_off1[4][64];
    __shared__ int s_cnt[4][2], s_k[4][2];
    const int t = threadIdx.x;
    const int g = t >> 6;                // board group within block
    const int q = t & 63;                // square
    const int b = blockIdx.x * 4 + g;

    s_off0[g][q] = 0; s_off1[g][q] = 0;
    if (q < 2) s_cnt[g][q] = 0;
    __syncthreads();

    if (b < nb) {
        const int d = boards[b * 64 + q];
        if (d == 0)       s_k[g][0] = q;
        else if (d == 12) s_k[g][1] = q;
        else if (d >= 1 && d <= 5) { int p = atomicAdd(&s_cnt[g][1], 1); s_off1[g][p] = (d - 1) * 64 + q; }
        else if (d >= 7 && d <= 11){ int p = atomicAdd(&s_cnt[g][0], 1); s_off0[g][p] = (11 - d) * 64 + q; }
    }
    __syncthreads();

    if (b < nb) {
        ws[WS_OFF0 + b * 64 + q] = s_off0[g][q];
        ws[WS_OFF1 + b * 64 + q] = s_off1[g][q];
        if (q == 0) {
            ws[WS_N0   + b] = s_cnt[g][0];
            ws[WS_N1   + b] = s_cnt[g][1];
            ws[WS_KMY  + b] = s_k[g][0];
            ws[WS_KOPP + b] = s_k[g][1];
        }
    }
}

// ---------------------------------------------------------------------------
// Node 2: bucketed first layer. Block = (m, king, rowgroup).
// Window staged row-major with ODD stride 325 -> conflict-free ds_read.
// Offsets live in 2 registers per lane, broadcast via __shfl(.,i,32):
// no goffs LDS, no barriers inside the board loop, simple prefetch pipeline.
// ---------------------------------------------------------------------------
__global__ __launch_bounds__(256) void gather_bucketed(
    const float* __restrict__ W_my, const float* __restrict__ W_opp,
    const float* __restrict__ b_my, const float* __restrict__ b_opp,
    const int* __restrict__ ws, float* __restrict__ h, int nb)
{
    __shared__ float win[32 * SLDS];     // 41.6 KB
    __shared__ int   s_list[NB_MAX];     // 4 KB
    __shared__ int   s_cnt;

    const int blk = blockIdx.x;          // 0..1023
    const int rg  = blk & 7;             // rowgroup (32 rows)
    const int k   = (blk >> 3) & 63;     // king square
    const int m   = blk >> 9;            // 0: W_my/opp-king, 1: W_opp/my-king
    const int t   = threadIdx.x;

    if (t == 0) s_cnt = 0;
    __syncthreads();

    const int* __restrict__ karr = ws + (m ? WS_KMY : WS_KOPP);
    for (int i = t; i < nb; i += 256)
        if (karr[i] == k) { int p = atomicAdd(&s_cnt, 1); s_list[p] = i; }
    __syncthreads();

    const int n_b = s_cnt;
    if (n_b == 0) return;

    // stage rows [rg*32, rg*32+32) x cols [cs, cs+324) at stride 325
    const int shift = (k * KBASE) & 3;
    const int cs    = k * KBASE - shift;
    const float* __restrict__ W = m ? W_opp : W_my;
    const size_t gbase = (size_t)(rg * 32) * FD + (size_t)cs;
    #pragma unroll
    for (int u = 0; u < 11; u++) {       // 32 rows * 81 float4 = 2592
        const int idx = u * 256 + t;
        if (idx < 2592) {
            const int r  = idx / 81;
            const int c4 = idx - r * 81;
            const float4 v = *(const float4*)(W + gbase + (size_t)r * FD + c4 * 4);
            float* dst = &win[r * SLDS + c4 * 4];   // odd stride: 4x ds_write_b32
            dst[0] = v.x; dst[1] = v.y; dst[2] = v.z; dst[3] = v.w;
        }
    }
    __syncthreads();

    const int* __restrict__ offarr = ws + (m ? WS_OFF1 : WS_OFF0);
    const int* __restrict__ narr   = ws + (m ? WS_N1   : WS_N0);
    const int r    = t & 31;
    const int slot = t >> 5;             // 8 boards in parallel, no cross-slot sync
    const float bias = (m ? b_opp : b_my)[rg * 32 + r];
    const int hcol = m * 256 + rg * 32 + r;
    const float* __restrict__ wrow = &win[r * SLDS + shift];

    int bi = slot;
    int board = -1, nf = 0, o0 = 0, o1 = 0;
    if (bi < n_b) {
        board = s_list[bi];
        nf = narr[board];
        o0 = offarr[board * 64 + r];          // coalesced 128B per slot
        o1 = offarr[board * 64 + 32 + r];
    }
    while (board >= 0) {
        // prefetch next board for this slot
        const int nbi = bi + 8;
        int nboard = -1, nnf = 0, no0 = 0, no1 = 0;
        if (nbi < n_b) {
            nboard = s_list[nbi];
            nnf = narr[nboard];
            no0 = offarr[nboard * 64 + r];
            no1 = offarr[nboard * 64 + 32 + r];
        }

        float acc0 = 0.0f, acc1 = 0.0f;
        const int lim = nf < 32 ? nf : 32;
        int i = 0;
        for (; i + 2 <= lim; i += 2) {
            acc0 += wrow[__shfl(o0, i,     32)];
            acc1 += wrow[__shfl(o0, i + 1, 32)];
        }
        if (i < lim) acc0 += wrow[__shfl(o0, i, 32)];
        i = 32;
        for (; i + 2 <= nf; i += 2) {
            acc0 += wrow[__shfl(o1, i - 32, 32)];
            acc1 += wrow[__shfl(o1, i - 31, 32)];
        }
        if (i < nf) acc0 += wrow[__shfl(o1, i - 32, 32)];

        h[(size_t)board * 512 + hcol] = fmaxf(acc0 + acc1 + bias, 0.0f);
        bi = nbi; board = nboard; nf = nnf; o0 = no0; o1 = no1;
    }
}

// ---------------------------------------------------------------------------
// Node 3: MLP tail. 4 boards per block; W1 staged once per block into LDS
// (stride 520 -> max 2-way = free), cutting W1 L2 traffic 4x.
// ---------------------------------------------------------------------------
__global__ __launch_bounds__(256) void mlp_tail4(
    const float* __restrict__ h,
    const float* __restrict__ W1, const float* __restrict__ b1,
    const float* __restrict__ W2, const float* __restrict__ b2,
    const float* __restrict__ W3, const float* __restrict__ b3,
    float* __restrict__ out, int nb)
{
    __shared__ float w1s[32 * W1S];      // 66.6 KB
    __shared__ float shh[4 * 512];       // 8 KB
    __shared__ float sh1[4 * 32];
    const int t  = threadIdx.x;
    const int b0 = blockIdx.x * 4;

    #pragma unroll
    for (int u = 0; u < 16; u++) {       // W1: 4096 float4, coalesced
        const int idx = u * 256 + t;
        const int o   = idx >> 7;
        const int c4  = idx & 127;
        const float4 v = *(const float4*)(W1 + o * 512 + c4 * 4);
        *(float4*)(&w1s[o * W1S + c4 * 4]) = v;
    }
    #pragma unroll
    for (int u = 0; u < 2; u++) {        // h for 4 boards: 512 float4
        const int idx = u * 256 + t;
        const int bl  = idx >> 7;
        const int c4  = idx & 127;
        float4 v = make_float4(0.f, 0.f, 0.f, 0.f);
        if (b0 + bl < nb) v = *(const float4*)(h + (size_t)(b0 + bl) * 512 + c4 * 4);
        *(float4*)(&shh[bl * 512 + c4 * 4]) = v;
    }
    __syncthreads();

    {
        const int o = t >> 3, l = t & 7;
        const float* __restrict__ w = &w1s[o * W1S];
        const float bb1 = b1[o];
        #pragma unroll
        for (int bl = 0; bl < 4; bl++) {
            const float* __restrict__ hb = &shh[bl * 512];
            float p = 0.0f;
            for (int kk = l; kk < 512; kk += 8) p += hb[kk] * w[kk];
            p += __shfl_down(p, 4, 8);
            p += __shfl_down(p, 2, 8);
            p += __shfl_down(p, 1, 8);
            if (l == 0) sh1[bl * 32 + o] = fmaxf(p + bb1, 0.0f);
        }
    }
    __syncthreads();

    if (t < 128) {                       // all 4 boards' tails in parallel
        const int bl = t >> 5, ln = t & 31;
        if (b0 + bl < nb) {
            const float* __restrict__ w2 = W2 + ln * 32;
            float acc = b2[ln];
            #pragma unroll
            for (int kk = 0; kk < 32; kk++) acc += sh1[bl * 32 + kk] * w2[kk];
            const float h2 = fmaxf(acc, 0.0f);
            float p = h2 * W3[ln];
            p += __shfl_down(p, 16, 32);
            p += __shfl_down(p,  8, 32);
            p += __shfl_down(p,  4, 32);
            p += __shfl_down(p,  2, 32);
            p += __shfl_down(p,  1, 32);
            if (ln == 0) out[b0 + bl] = p + b3[0];
        }
    }
}

// ---------------------------------------------------------------------------
// Fallback: direct strided gather — used only if d_ws too small.
// ---------------------------------------------------------------------------
__global__ __launch_bounds__(256) void nnue_fwd(
    const int*   __restrict__ boards,
    const float* __restrict__ W_my,  const float* __restrict__ b_my,
    const float* __restrict__ W_opp, const float* __restrict__ b_opp,
    const float* __restrict__ W1,    const float* __restrict__ b1,
    const float* __restrict__ W2,    const float* __restrict__ b2,
    const float* __restrict__ W3,    const float* __restrict__ b3,
    float* __restrict__ out)
{
    __shared__ int   s_off0[64], s_off1[64];
    __shared__ int   s_cnt[2], s_kings[2];
    __shared__ float s_h[512];
    __shared__ float s_h1[32];

    const int b = blockIdx.x;
    const int t = threadIdx.x;

    if (t < 2) s_cnt[t] = 0;
    __syncthreads();

    if (t < 64) {
        int d = boards[b * 64 + t];
        if (d == 0)       s_kings[0] = t;
        else if (d == 12) s_kings[1] = t;
        else if (d >= 1 && d <= 5) { int p = atomicAdd(&s_cnt[1], 1); s_off1[p] = (d - 1) * 64 + t; }
        else if (d >= 7)           { int p = atomicAdd(&s_cnt[0], 1); s_off0[p] = (11 - d) * 64 + t; }
    }
    __syncthreads();

    const int n0 = s_cnt[0], n1 = s_cnt[1];
    const int base0 = s_kings[1] * KBASE;
    const int base1 = s_kings[0] * KBASE;

    {
        const float* __restrict__ w = W_my + (size_t)t * FD + base0;
        float acc = b_my[t];
        for (int i = 0; i < n0; i++) acc += w[s_off0[i]];
        s_h[t] = fmaxf(acc, 0.0f);
    }
    {
        const float* __restrict__ w = W_opp + (size_t)t * FD + base1;
        float acc = b_opp[t];
        for (int i = 0; i < n1; i++) acc += w[s_off1[i]];
        s_h[256 + t] = fmaxf(acc, 0.0f);
    }
    __syncthreads();

    {
        const int o = t >> 3, l = t & 7;
        const float* __restrict__ w = W1 + o * 512;
        float p = 0.0f;
        for (int kk = l; kk < 512; kk += 8) p += s_h[kk] * w[kk];
        p += __shfl_down(p, 4, 8);
        p += __shfl_down(p, 2, 8);
        p += __shfl_down(p, 1, 8);
        if (l == 0) s_h1[o] = fmaxf(p + b1[o], 0.0f);
    }
    __syncthreads();

    if (t < 32) {
        const float* __restrict__ w = W2 + t * 32;
        float acc = b2[t];
        for (int kk = 0; kk < 32; kk++) acc += s_h1[kk] * w[kk];
        float h2 = fmaxf(acc, 0.0f);
        float p = h2 * W3[t];
        p += __shfl_down(p, 16, 32);
        p += __shfl_down(p,  8, 32);
        p += __shfl_down(p,  4, 32);
        p += __shfl_down(p,  2, 32);
        p += __shfl_down(p,  1, 32);
        if (t == 0) out[b] = p + b3[0];
    }
}

extern "C" void kernel_launch(void* const* d_in, const int* in_sizes, int n_in,
                              void* d_out, int out_size, void* d_ws, size_t ws_size,
                              hipStream_t stream) {
    const int*   boards = (const int*)  d_in[0];
    const float* W_my   = (const float*)d_in[1];
    const float* b_my   = (const float*)d_in[2];
    const float* W_opp  = (const float*)d_in[3];
    const float* b_opp  = (const float*)d_in[4];
    const float* W1     = (const float*)d_in[5];
    const float* b1     = (const float*)d_in[6];
    const float* W2     = (const float*)d_in[7];
    const float* b2     = (const float*)d_in[8];
    const float* W3     = (const float*)d_in[9];
    const float* b3     = (const float*)d_in[10];
    float* out = (float*)d_out;

    const int nb = in_sizes[0] / 64;
    const size_t ws_needed = (size_t)(WS_H + (size_t)NB_MAX * 512) * sizeof(int);

    if (nb <= NB_MAX && ws_size >= ws_needed) {
        int*   wsi = (int*)d_ws;
        float* h   = (float*)d_ws + WS_H;
        const int nb4 = (nb + 3) / 4;
        classify4<<<nb4, 256, 0, stream>>>(boards, wsi, nb);
        gather_bucketed<<<1024, 256, 0, stream>>>(W_my, W_opp, b_my, b_opp, wsi, h, nb);
        mlp_tail4<<<nb4, 256, 0, stream>>>(h, W1, b1, W2, b2, W3, b3, out, nb);
    } else {
        nnue_fwd<<<nb, 256, 0, stream>>>(boards, W_my, b_my, W_opp, b_opp,
                                         W1, b1, W2, b2, W3, b3, out);
    }
}